// Round 7
// baseline (234.805 us; speedup 1.0000x reference)
//
#include <hip/hip_runtime.h>
#include <hip/hip_bf16.h>

typedef __attribute__((ext_vector_type(8))) __bf16 bf16x8;
typedef __attribute__((ext_vector_type(4))) float f32x4;

#define ALPHA 0.999f
#define THETA 0.05f

#define K1_BLOCKS 512
#define K1_WAVES 16
// Per-wave region: 32 rows x 50 halfs (3200 B). 50-half stride (25 dwords,
// gcd(25,32)=1) proven 0-conflict in R1-R6. Phase A: dy@0(16) | h@16(32).
// Phase B overlays: dh@0(32) | q@32(16). Each 64-row batch is staged in two
// 32-row sub-phases (lanes 0-31 then 32-63) so 16 waves fit in 51.2 KB.
#define RREC 50
#define F_DY 0
#define F_H  16
#define F_DH 0
#define F_Q  32
#define WAVE_REGION_HALFS (32*RREC)       // 1600 halfs = 3200 B
#define SMEM_BYTES 57344                  // max(16*3200=51200, 8*1792*4=57344)

__device__ __forceinline__ float sigmoidf_(float z){ return 1.f/(1.f+__expf(-z)); }

__device__ __forceinline__ unsigned pk2_(float a, float b){
  union { __bf16 h[2]; unsigned u; } x; x.h[0]=(__bf16)a; x.h[1]=(__bf16)b; return x.u;
}

// ---------------- Kernel 1: gradient pass -> per-block partial sums ----------------
// Toolchain VGPR rule (measured R1-R6): cap = 512 / (2 * second-launch-bounds
// arg); bare 1024-thread kernels default to 8 waves/SIMD -> 64 VGPR -> massive
// scratch spill (R6: 466 MB spill traffic). (1024,2) targets 4 waves/SIMD ->
// cap 128 >= the ~116 this body needs, with one 16-wave block resident (50%).
__global__ __launch_bounds__(1024, 2)
void k1_grad(const float* __restrict__ X,
             const float* __restrict__ W0, const float* __restrict__ b0,
             const float* __restrict__ W1, const float* __restrict__ b1,
             const float* __restrict__ WV, const float* __restrict__ WQ,
             float* __restrict__ wsPart, int N)
{
  __shared__ __align__(16) unsigned char smem_raw[SMEM_BYTES];
  const int tid = threadIdx.x;
  const int w = tid >> 6, l = tid & 63;
  __bf16* WB = (__bf16*)smem_raw + w*WAVE_REGION_HALFS;

  bf16x8 ones;
  #pragma unroll
  for (int i=0;i<8;++i) ones[i] = (__bf16)1.f;

  f32x4 acc[7] = {};

  const int nb = N >> 6;                 // 64-row batches
  const int tw = K1_BLOCKS*K1_WAVES;     // total waves
  const int gw = blockIdx.x*K1_WAVES + w;
  const int iters = (nb + tw - 1) / tw;

  const int c = l & 15;
  const int r0 = (l>>4)<<3;

  for (int it = 0; it < iters; ++it) {
    const int batch = gw + it*tw;
    const bool active = (batch < nb);

    if (active) {
      const int row = (batch<<6) + l;
      const float* xp = X + (size_t)row*16;
      float x[16];
      {
        const float4* xv = (const float4*)xp;
        float4 t0=xv[0], t1=xv[1], t2=xv[2], t3=xv[3];
        x[0]=t0.x; x[1]=t0.y; x[2]=t0.z; x[3]=t0.w;
        x[4]=t1.x; x[5]=t1.y; x[6]=t1.z; x[7]=t1.w;
        x[8]=t2.x; x[9]=t2.y; x[10]=t2.z; x[11]=t2.w;
        x[12]=t3.x; x[13]=t3.y; x[14]=t3.z; x[15]=t3.w;
      }
      // v = silu(x @ WV^T)
      float vv[16];
      #pragma unroll
      for (int k=0;k<16;++k){
        float s = 0.f;
        #pragma unroll
        for (int d=0;d<16;++d) s = fmaf(x[d], WV[k*16+d], s);
        vv[k] = s * sigmoidf_(s);
      }
      // q = l2norm(silu(x @ WQ^T))   (x dies here)
      float q[16]; float n2 = 0.f;
      #pragma unroll
      for (int k=0;k<16;++k){
        float s = 0.f;
        #pragma unroll
        for (int d=0;d<16;++d) s = fmaf(x[d], WQ[k*16+d], s);
        float t = s * sigmoidf_(s);
        q[k] = t; n2 = fmaf(t, t, n2);
      }
      const float inv = 1.f / fmaxf(sqrtf(n2), 1e-12f);
      #pragma unroll
      for (int k=0;k<16;++k) q[k] *= inv;
      // h = silu(q @ W0^T + b0), keep dsilu
      float h[32], dsh[32];
      #pragma unroll
      for (int j=0;j<32;++j){
        float s = b0[j];
        #pragma unroll
        for (int d=0;d<16;++d) s = fmaf(q[d], W0[j*16+d], s);
        float sg = sigmoidf_(s);
        h[j] = s*sg;
        dsh[j] = sg * fmaf(s, 1.f - sg, 1.f);
      }
      // y, dy (unscaled; scale applied in k2b). vv dies here.
      float dy[16];
      #pragma unroll
      for (int k=0;k<16;++k){
        float s = b1[k];
        #pragma unroll
        for (int j=0;j<32;++j) s = fmaf(h[j], W1[k*32+j], s);
        float sg = sigmoidf_(s);
        float y = s*sg;
        float ds = sg * fmaf(s, 1.f - sg, 1.f);
        dy[k] = (y - vv[k]) * ds;
      }

      // ---- Phase A: [dy|h] staged 32 rows at a time; 2x3 MFMAs ----
      // Same-wave DS in-order (proven R4-R6): frag reads of sub-phase 1
      // complete before sub-phase 2's writes land.
      #pragma unroll
      for (int sp=0; sp<2; ++sp){
        const bool mine = (l>>5) == sp;
        if (mine){
          __bf16* R = WB + (l&31)*RREC;
          uint2* p = (uint2*)(R + F_DY);
          #pragma unroll
          for (int k=0;k<16;k+=4) p[k>>2] = make_uint2(pk2_(dy[k],dy[k+1]), pk2_(dy[k+2],dy[k+3]));
          uint2* ph = (uint2*)(R + F_H);
          #pragma unroll
          for (int j=0;j<32;j+=4) ph[j>>2] = make_uint2(pk2_(h[j],h[j+1]), pk2_(h[j+2],h[j+3]));
        }
        const __bf16* base = WB + r0*RREC + c;
        bf16x8 fdy, fh0, fh1;
        #pragma unroll
        for (int i=0;i<8;++i){
          const __bf16* pr = base + i*RREC;
          fdy[i] = pr[F_DY];
          fh0[i] = pr[F_H];
          fh1[i] = pr[F_H + 16];
        }
        acc[0] = __builtin_amdgcn_mfma_f32_16x16x32_bf16(fdy, fh0, acc[0], 0,0,0); // gW1[:, 0:16]
        acc[1] = __builtin_amdgcn_mfma_f32_16x16x32_bf16(fdy, fh1, acc[1], 0,0,0); // gW1[:,16:32]
        acc[2] = __builtin_amdgcn_mfma_f32_16x16x32_bf16(fdy, ones, acc[2], 0,0,0); // gb1
      }

      // dh = (dy @ W1) * dsilu  (dy, dsh die here; h died at staging)
      float dh[32];
      #pragma unroll
      for (int j=0;j<32;++j){
        float s = 0.f;
        #pragma unroll
        for (int k=0;k<16;++k) s = fmaf(dy[k], W1[k*32+j], s);
        dh[j] = s * dsh[j];
      }

      // ---- Phase B: [dh|q] overlays the region; 2x4 MFMAs ----
      #pragma unroll
      for (int sp=0; sp<2; ++sp){
        const bool mine = (l>>5) == sp;
        if (mine){
          __bf16* R = WB + (l&31)*RREC;
          uint2* p = (uint2*)(R + F_DH);
          #pragma unroll
          for (int j=0;j<32;j+=4) p[j>>2] = make_uint2(pk2_(dh[j],dh[j+1]), pk2_(dh[j+2],dh[j+3]));
          uint2* pq = (uint2*)(R + F_Q);
          #pragma unroll
          for (int k=0;k<16;k+=4) pq[k>>2] = make_uint2(pk2_(q[k],q[k+1]), pk2_(q[k+2],q[k+3]));
        }
        const __bf16* base = WB + r0*RREC + c;
        bf16x8 fd0, fd1, fq;
        #pragma unroll
        for (int i=0;i<8;++i){
          const __bf16* pr = base + i*RREC;
          fd0[i] = pr[F_DH];
          fd1[i] = pr[F_DH + 16];
          fq[i]  = pr[F_Q];
        }
        acc[3] = __builtin_amdgcn_mfma_f32_16x16x32_bf16(fd0, fq, acc[3], 0,0,0);   // gW0[0:16, :]
        acc[4] = __builtin_amdgcn_mfma_f32_16x16x32_bf16(fd1, fq, acc[4], 0,0,0);   // gW0[16:32,:]
        acc[5] = __builtin_amdgcn_mfma_f32_16x16x32_bf16(fd0, ones, acc[5], 0,0,0); // gb0[0:16]
        acc[6] = __builtin_amdgcn_mfma_f32_16x16x32_bf16(fd1, ones, acc[6], 0,0,0); // gb0[16:32]
      }
    }
  }

  // ---- block reduction over 16 waves (two-stage, 8 slots x 1792 floats) ----
  __syncthreads();
  float* red = (float*)smem_raw;
  if (w < 8){
    #pragma unroll
    for (int a=0;a<7;++a){
      #pragma unroll
      for (int r=0;r<4;++r)
        red[w*1792 + a*256 + l*4 + r] = acc[a][r];
    }
  }
  __syncthreads();
  if (w >= 8){
    #pragma unroll
    for (int a=0;a<7;++a){
      #pragma unroll
      for (int r=0;r<4;++r)
        red[(w-8)*1792 + a*256 + l*4 + r] += acc[a][r];
    }
  }
  __syncthreads();
  for (int s = tid; s < 1792; s += 1024){
    float sum = 0.f;
    #pragma unroll
    for (int k=0;k<8;++k) sum += red[k*1792 + s];
    wsPart[(size_t)blockIdx.x*1792 + s] = sum;
  }
}

// ---------------- Kernel 2a: partial reduce (512 -> 16 chunks) ----------------
__global__ void k2a_reduce(const float* __restrict__ wsPart, float* __restrict__ tmp)
{
  const int s = blockIdx.x*256 + threadIdx.x;   // 0..1791 (grid.x = 7)
  const int c = blockIdx.y;                     // 0..15
  float g = 0.f;
  #pragma unroll 8
  for (int j=0;j<32;++j) g += wsPart[(size_t)(c*32+j)*1792 + s];
  tmp[(size_t)c*1792 + s] = g;
}

// ---------------- Kernel 2b: final reduce, form updated params ----------------
__global__ void k2b_reduce(const float* __restrict__ tmp,
                           const float* __restrict__ W0, const float* __restrict__ b0,
                           const float* __restrict__ W1, const float* __restrict__ b1,
                           float* __restrict__ P, float scale)
{
  int s = blockIdx.x*256 + threadIdx.x;
  if (s >= 1792) return;
  float g = 0.f;
  #pragma unroll
  for (int c=0;c<16;++c) g += tmp[(size_t)c*1792 + s];
  g *= scale;   // 2/(N*16)
  int a = s >> 8, l = (s >> 2) & 63, r = s & 3;
  int m = ((l>>4)<<2) + r, n = l & 15;
  // P layout (floats): W0[0..511], b0[512..543], W1[544..1055], b1[1056..1071]
  if (a==0)      P[544 + m*32 + n]       = ALPHA*W1[m*32+n]        - THETA*g;
  else if (a==1) P[544 + m*32 + 16 + n]  = ALPHA*W1[m*32+16+n]     - THETA*g;
  else if (a==2){ if (n==0) P[1056 + m]  = ALPHA*b1[m]             - THETA*g; }
  else if (a==3) P[m*16 + n]             = ALPHA*W0[m*16+n]        - THETA*g;
  else if (a==4) P[(16+m)*16 + n]        = ALPHA*W0[(16+m)*16+n]   - THETA*g;
  else if (a==5){ if (n==0) P[512 + m]   = ALPHA*b0[m]             - THETA*g; }
  else           { if (n==0) P[512+16+m] = ALPHA*b0[16+m]          - THETA*g; }
}

// ---------------- Kernel 3: retrieve pass ----------------
__global__ __launch_bounds__(256)
void k3_retrieve(const float* __restrict__ X, const float* __restrict__ WQ,
                 const float* __restrict__ P, float* __restrict__ out, int N)
{
  int row = blockIdx.x*256 + threadIdx.x;
  if (row >= N) return;
  const float* xp = X + (size_t)row*16;
  float x[16];
  {
    const float4* xv = (const float4*)xp;
    float4 t0=xv[0], t1=xv[1], t2=xv[2], t3=xv[3];
    x[0]=t0.x; x[1]=t0.y; x[2]=t0.z; x[3]=t0.w;
    x[4]=t1.x; x[5]=t1.y; x[6]=t1.z; x[7]=t1.w;
    x[8]=t2.x; x[9]=t2.y; x[10]=t2.z; x[11]=t2.w;
    x[12]=t3.x; x[13]=t3.y; x[14]=t3.z; x[15]=t3.w;
  }
  // r = silu(l2norm(x @ WQ^T))   (note: norm BEFORE silu here)
  float rq[16]; float n2 = 0.f;
  #pragma unroll
  for (int k=0;k<16;++k){
    float s = 0.f;
    #pragma unroll
    for (int d=0;d<16;++d) s = fmaf(x[d], WQ[k*16+d], s);
    rq[k] = s; n2 = fmaf(s, s, n2);
  }
  const float inv = 1.f / fmaxf(sqrtf(n2), 1e-12f);
  #pragma unroll
  for (int k=0;k<16;++k){
    float z = rq[k]*inv;
    rq[k] = z * sigmoidf_(z);
  }
  // h = silu(r @ W0'^T + b0')
  float h[32];
  #pragma unroll
  for (int j=0;j<32;++j){
    float s = P[512+j];
    #pragma unroll
    for (int d=0;d<16;++d) s = fmaf(rq[d], P[j*16+d], s);
    h[j] = s * sigmoidf_(s);
  }
  // o = silu(h @ W1'^T + b1')
  float o[16];
  #pragma unroll
  for (int k=0;k<16;++k){
    float s = P[1056+k];
    #pragma unroll
    for (int j=0;j<32;++j) s = fmaf(h[j], P[544 + k*32 + j], s);
    o[k] = s * sigmoidf_(s);
  }
  float4* op = (float4*)(out + (size_t)row*16);
  op[0] = make_float4(o[0],o[1],o[2],o[3]);
  op[1] = make_float4(o[4],o[5],o[6],o[7]);
  op[2] = make_float4(o[8],o[9],o[10],o[11]);
  op[3] = make_float4(o[12],o[13],o[14],o[15]);
}

extern "C" void kernel_launch(void* const* d_in, const int* in_sizes, int n_in,
                              void* d_out, int out_size, void* d_ws, size_t ws_size,
                              hipStream_t stream)
{
  const float* X  = (const float*)d_in[0];
  const float* W0 = (const float*)d_in[1];
  const float* b0 = (const float*)d_in[2];
  const float* W1 = (const float*)d_in[3];
  const float* b1 = (const float*)d_in[4];
  const float* WV = (const float*)d_in[6];
  const float* WQ = (const float*)d_in[7];
  float* ws   = (float*)d_ws;
  float* P    = ws;                         // 1072 floats of updated params
  float* part = ws + 2048;                  // 512*1792 floats of partials
  float* tmp  = part + (size_t)K1_BLOCKS*1792;  // 16*1792 floats

  const int N = in_sizes[0] / 16;
  const float scale = 2.f / (16.f * (float)N);

  k1_grad<<<dim3(K1_BLOCKS), dim3(1024), 0, stream>>>(X, W0, b0, W1, b1, WV, WQ, part, N);
  k2a_reduce<<<dim3(7,16), dim3(256), 0, stream>>>(part, tmp);
  k2b_reduce<<<dim3(7), dim3(256), 0, stream>>>(tmp, W0, b0, W1, b1, P, scale);
  k3_retrieve<<<dim3((N+255)/256), dim3(256), 0, stream>>>(X, WQ, P, (float*)d_out, N);
}

// Round 8
// 234.405 us; speedup vs baseline: 1.0017x; 1.0017x over previous
//
#include <hip/hip_runtime.h>
#include <hip/hip_bf16.h>

typedef __attribute__((ext_vector_type(8))) __bf16 bf16x8;
typedef __attribute__((ext_vector_type(4))) float f32x4;

#define ALPHA 0.999f
#define THETA 0.05f

#define K1_BLOCKS 512
#define K1_WAVES 16
// Per-wave region: 32 rows x 50 halfs (3200 B). 50-half stride (25 dwords,
// gcd(25,32)=1) proven 0-conflict in R1-R7. Phase A: dy@0(16) | h@16(32).
// Phase B overlays: dh@0(32) | q@32(16). Each 64-row batch is staged in two
// 32-row sub-phases (lanes 0-31 then 32-63) so 16 waves fit in 51.2 KB.
#define RREC 50
#define F_DY 0
#define F_H  16
#define F_DH 0
#define F_Q  32
#define WAVE_REGION_HALFS (32*RREC)       // 1600 halfs = 3200 B
#define SMEM_BYTES 57344                  // max(16*3200=51200, 8*1792*4=57344)

__device__ __forceinline__ float sigmoidf_(float z){ return 1.f/(1.f+__expf(-z)); }

__device__ __forceinline__ unsigned pk2_(float a, float b){
  union { __bf16 h[2]; unsigned u; } x; x.h[0]=(__bf16)a; x.h[1]=(__bf16)b; return x.u;
}

// ---------------- Kernel 1: gradient pass -> per-block partial sums ----------------
// Occupancy/VGPR history: launch_bounds 2nd arg is only a MIN waves/EU (lowers
// the VGPR cap when it binds, never raises the backend's target). For 1024-thr
// blocks the backend targets 8 waves/EU -> 64 VGPR -> ~466 MB scratch spill
// (R6/R7). amdgpu_waves_per_eu(4,4) pins the target: cap 512/4 = 128 >= ~116
// needed -> no spill, one 16-wave block resident (50% occupancy).
__global__ __launch_bounds__(1024)
__attribute__((amdgpu_waves_per_eu(4, 4)))
void k1_grad(const float* __restrict__ X,
             const float* __restrict__ W0, const float* __restrict__ b0,
             const float* __restrict__ W1, const float* __restrict__ b1,
             const float* __restrict__ WV, const float* __restrict__ WQ,
             float* __restrict__ wsPart, int N)
{
  __shared__ __align__(16) unsigned char smem_raw[SMEM_BYTES];
  const int tid = threadIdx.x;
  const int w = tid >> 6, l = tid & 63;
  __bf16* WB = (__bf16*)smem_raw + w*WAVE_REGION_HALFS;

  bf16x8 ones;
  #pragma unroll
  for (int i=0;i<8;++i) ones[i] = (__bf16)1.f;

  f32x4 acc[7] = {};

  const int nb = N >> 6;                 // 64-row batches
  const int tw = K1_BLOCKS*K1_WAVES;     // total waves
  const int gw = blockIdx.x*K1_WAVES + w;
  const int iters = (nb + tw - 1) / tw;

  const int c = l & 15;
  const int r0 = (l>>4)<<3;

  for (int it = 0; it < iters; ++it) {
    const int batch = gw + it*tw;
    const bool active = (batch < nb);

    if (active) {
      const int row = (batch<<6) + l;
      const float* xp = X + (size_t)row*16;
      float x[16];
      {
        const float4* xv = (const float4*)xp;
        float4 t0=xv[0], t1=xv[1], t2=xv[2], t3=xv[3];
        x[0]=t0.x; x[1]=t0.y; x[2]=t0.z; x[3]=t0.w;
        x[4]=t1.x; x[5]=t1.y; x[6]=t1.z; x[7]=t1.w;
        x[8]=t2.x; x[9]=t2.y; x[10]=t2.z; x[11]=t2.w;
        x[12]=t3.x; x[13]=t3.y; x[14]=t3.z; x[15]=t3.w;
      }
      // v = silu(x @ WV^T)
      float vv[16];
      #pragma unroll
      for (int k=0;k<16;++k){
        float s = 0.f;
        #pragma unroll
        for (int d=0;d<16;++d) s = fmaf(x[d], WV[k*16+d], s);
        vv[k] = s * sigmoidf_(s);
      }
      // q = l2norm(silu(x @ WQ^T))   (x dies here)
      float q[16]; float n2 = 0.f;
      #pragma unroll
      for (int k=0;k<16;++k){
        float s = 0.f;
        #pragma unroll
        for (int d=0;d<16;++d) s = fmaf(x[d], WQ[k*16+d], s);
        float t = s * sigmoidf_(s);
        q[k] = t; n2 = fmaf(t, t, n2);
      }
      const float inv = 1.f / fmaxf(sqrtf(n2), 1e-12f);
      #pragma unroll
      for (int k=0;k<16;++k) q[k] *= inv;
      // h = silu(q @ W0^T + b0), keep dsilu
      float h[32], dsh[32];
      #pragma unroll
      for (int j=0;j<32;++j){
        float s = b0[j];
        #pragma unroll
        for (int d=0;d<16;++d) s = fmaf(q[d], W0[j*16+d], s);
        float sg = sigmoidf_(s);
        h[j] = s*sg;
        dsh[j] = sg * fmaf(s, 1.f - sg, 1.f);
      }
      // y, dy (unscaled; scale applied in k2b). vv dies here.
      float dy[16];
      #pragma unroll
      for (int k=0;k<16;++k){
        float s = b1[k];
        #pragma unroll
        for (int j=0;j<32;++j) s = fmaf(h[j], W1[k*32+j], s);
        float sg = sigmoidf_(s);
        float y = s*sg;
        float ds = sg * fmaf(s, 1.f - sg, 1.f);
        dy[k] = (y - vv[k]) * ds;
      }

      // ---- Phase A: [dy|h] staged 32 rows at a time; 2x3 MFMAs ----
      // Same-wave DS in-order (proven R4-R7): frag reads of sub-phase 1
      // complete before sub-phase 2's writes land.
      #pragma unroll
      for (int sp=0; sp<2; ++sp){
        const bool mine = (l>>5) == sp;
        if (mine){
          __bf16* R = WB + (l&31)*RREC;
          uint2* p = (uint2*)(R + F_DY);
          #pragma unroll
          for (int k=0;k<16;k+=4) p[k>>2] = make_uint2(pk2_(dy[k],dy[k+1]), pk2_(dy[k+2],dy[k+3]));
          uint2* ph = (uint2*)(R + F_H);
          #pragma unroll
          for (int j=0;j<32;j+=4) ph[j>>2] = make_uint2(pk2_(h[j],h[j+1]), pk2_(h[j+2],h[j+3]));
        }
        const __bf16* base = WB + r0*RREC + c;
        bf16x8 fdy, fh0, fh1;
        #pragma unroll
        for (int i=0;i<8;++i){
          const __bf16* pr = base + i*RREC;
          fdy[i] = pr[F_DY];
          fh0[i] = pr[F_H];
          fh1[i] = pr[F_H + 16];
        }
        acc[0] = __builtin_amdgcn_mfma_f32_16x16x32_bf16(fdy, fh0, acc[0], 0,0,0); // gW1[:, 0:16]
        acc[1] = __builtin_amdgcn_mfma_f32_16x16x32_bf16(fdy, fh1, acc[1], 0,0,0); // gW1[:,16:32]
        acc[2] = __builtin_amdgcn_mfma_f32_16x16x32_bf16(fdy, ones, acc[2], 0,0,0); // gb1
      }

      // dh = (dy @ W1) * dsilu  (dy, dsh die here; h died at staging)
      float dh[32];
      #pragma unroll
      for (int j=0;j<32;++j){
        float s = 0.f;
        #pragma unroll
        for (int k=0;k<16;++k) s = fmaf(dy[k], W1[k*32+j], s);
        dh[j] = s * dsh[j];
      }

      // ---- Phase B: [dh|q] overlays the region; 2x4 MFMAs ----
      #pragma unroll
      for (int sp=0; sp<2; ++sp){
        const bool mine = (l>>5) == sp;
        if (mine){
          __bf16* R = WB + (l&31)*RREC;
          uint2* p = (uint2*)(R + F_DH);
          #pragma unroll
          for (int j=0;j<32;j+=4) p[j>>2] = make_uint2(pk2_(dh[j],dh[j+1]), pk2_(dh[j+2],dh[j+3]));
          uint2* pq = (uint2*)(R + F_Q);
          #pragma unroll
          for (int k=0;k<16;k+=4) pq[k>>2] = make_uint2(pk2_(q[k],q[k+1]), pk2_(q[k+2],q[k+3]));
        }
        const __bf16* base = WB + r0*RREC + c;
        bf16x8 fd0, fd1, fq;
        #pragma unroll
        for (int i=0;i<8;++i){
          const __bf16* pr = base + i*RREC;
          fd0[i] = pr[F_DH];
          fd1[i] = pr[F_DH + 16];
          fq[i]  = pr[F_Q];
        }
        acc[3] = __builtin_amdgcn_mfma_f32_16x16x32_bf16(fd0, fq, acc[3], 0,0,0);   // gW0[0:16, :]
        acc[4] = __builtin_amdgcn_mfma_f32_16x16x32_bf16(fd1, fq, acc[4], 0,0,0);   // gW0[16:32,:]
        acc[5] = __builtin_amdgcn_mfma_f32_16x16x32_bf16(fd0, ones, acc[5], 0,0,0); // gb0[0:16]
        acc[6] = __builtin_amdgcn_mfma_f32_16x16x32_bf16(fd1, ones, acc[6], 0,0,0); // gb0[16:32]
      }
    }
  }

  // ---- block reduction over 16 waves (two-stage, 8 slots x 1792 floats) ----
  __syncthreads();
  float* red = (float*)smem_raw;
  if (w < 8){
    #pragma unroll
    for (int a=0;a<7;++a){
      #pragma unroll
      for (int r=0;r<4;++r)
        red[w*1792 + a*256 + l*4 + r] = acc[a][r];
    }
  }
  __syncthreads();
  if (w >= 8){
    #pragma unroll
    for (int a=0;a<7;++a){
      #pragma unroll
      for (int r=0;r<4;++r)
        red[(w-8)*1792 + a*256 + l*4 + r] += acc[a][r];
    }
  }
  __syncthreads();
  for (int s = tid; s < 1792; s += 1024){
    float sum = 0.f;
    #pragma unroll
    for (int k=0;k<8;++k) sum += red[k*1792 + s];
    wsPart[(size_t)blockIdx.x*1792 + s] = sum;
  }
}

// ---------------- Kernel 2a: partial reduce (512 -> 16 chunks) ----------------
__global__ void k2a_reduce(const float* __restrict__ wsPart, float* __restrict__ tmp)
{
  const int s = blockIdx.x*256 + threadIdx.x;   // 0..1791 (grid.x = 7)
  const int c = blockIdx.y;                     // 0..15
  float g = 0.f;
  #pragma unroll 8
  for (int j=0;j<32;++j) g += wsPart[(size_t)(c*32+j)*1792 + s];
  tmp[(size_t)c*1792 + s] = g;
}

// ---------------- Kernel 2b: final reduce, form updated params ----------------
__global__ void k2b_reduce(const float* __restrict__ tmp,
                           const float* __restrict__ W0, const float* __restrict__ b0,
                           const float* __restrict__ W1, const float* __restrict__ b1,
                           float* __restrict__ P, float scale)
{
  int s = blockIdx.x*256 + threadIdx.x;
  if (s >= 1792) return;
  float g = 0.f;
  #pragma unroll
  for (int c=0;c<16;++c) g += tmp[(size_t)c*1792 + s];
  g *= scale;   // 2/(N*16)
  int a = s >> 8, l = (s >> 2) & 63, r = s & 3;
  int m = ((l>>4)<<2) + r, n = l & 15;
  // P layout (floats): W0[0..511], b0[512..543], W1[544..1055], b1[1056..1071]
  if (a==0)      P[544 + m*32 + n]       = ALPHA*W1[m*32+n]        - THETA*g;
  else if (a==1) P[544 + m*32 + 16 + n]  = ALPHA*W1[m*32+16+n]     - THETA*g;
  else if (a==2){ if (n==0) P[1056 + m]  = ALPHA*b1[m]             - THETA*g; }
  else if (a==3) P[m*16 + n]             = ALPHA*W0[m*16+n]        - THETA*g;
  else if (a==4) P[(16+m)*16 + n]        = ALPHA*W0[(16+m)*16+n]   - THETA*g;
  else if (a==5){ if (n==0) P[512 + m]   = ALPHA*b0[m]             - THETA*g; }
  else           { if (n==0) P[512+16+m] = ALPHA*b0[16+m]          - THETA*g; }
}

// ---------------- Kernel 3: retrieve pass ----------------
__global__ __launch_bounds__(256)
void k3_retrieve(const float* __restrict__ X, const float* __restrict__ WQ,
                 const float* __restrict__ P, float* __restrict__ out, int N)
{
  int row = blockIdx.x*256 + threadIdx.x;
  if (row >= N) return;
  const float* xp = X + (size_t)row*16;
  float x[16];
  {
    const float4* xv = (const float4*)xp;
    float4 t0=xv[0], t1=xv[1], t2=xv[2], t3=xv[3];
    x[0]=t0.x; x[1]=t0.y; x[2]=t0.z; x[3]=t0.w;
    x[4]=t1.x; x[5]=t1.y; x[6]=t1.z; x[7]=t1.w;
    x[8]=t2.x; x[9]=t2.y; x[10]=t2.z; x[11]=t2.w;
    x[12]=t3.x; x[13]=t3.y; x[14]=t3.z; x[15]=t3.w;
  }
  // r = silu(l2norm(x @ WQ^T))   (note: norm BEFORE silu here)
  float rq[16]; float n2 = 0.f;
  #pragma unroll
  for (int k=0;k<16;++k){
    float s = 0.f;
    #pragma unroll
    for (int d=0;d<16;++d) s = fmaf(x[d], WQ[k*16+d], s);
    rq[k] = s; n2 = fmaf(s, s, n2);
  }
  const float inv = 1.f / fmaxf(sqrtf(n2), 1e-12f);
  #pragma unroll
  for (int k=0;k<16;++k){
    float z = rq[k]*inv;
    rq[k] = z * sigmoidf_(z);
  }
  // h = silu(r @ W0'^T + b0')
  float h[32];
  #pragma unroll
  for (int j=0;j<32;++j){
    float s = P[512+j];
    #pragma unroll
    for (int d=0;d<16;++d) s = fmaf(rq[d], P[j*16+d], s);
    h[j] = s * sigmoidf_(s);
  }
  // o = silu(h @ W1'^T + b1')
  float o[16];
  #pragma unroll
  for (int k=0;k<16;++k){
    float s = P[1056+k];
    #pragma unroll
    for (int j=0;j<32;++j) s = fmaf(h[j], P[544 + k*32 + j], s);
    o[k] = s * sigmoidf_(s);
  }
  float4* op = (float4*)(out + (size_t)row*16);
  op[0] = make_float4(o[0],o[1],o[2],o[3]);
  op[1] = make_float4(o[4],o[5],o[6],o[7]);
  op[2] = make_float4(o[8],o[9],o[10],o[11]);
  op[3] = make_float4(o[12],o[13],o[14],o[15]);
}

extern "C" void kernel_launch(void* const* d_in, const int* in_sizes, int n_in,
                              void* d_out, int out_size, void* d_ws, size_t ws_size,
                              hipStream_t stream)
{
  const float* X  = (const float*)d_in[0];
  const float* W0 = (const float*)d_in[1];
  const float* b0 = (const float*)d_in[2];
  const float* W1 = (const float*)d_in[3];
  const float* b1 = (const float*)d_in[4];
  const float* WV = (const float*)d_in[6];
  const float* WQ = (const float*)d_in[7];
  float* ws   = (float*)d_ws;
  float* P    = ws;                         // 1072 floats of updated params
  float* part = ws + 2048;                  // 512*1792 floats of partials
  float* tmp  = part + (size_t)K1_BLOCKS*1792;  // 16*1792 floats

  const int N = in_sizes[0] / 16;
  const float scale = 2.f / (16.f * (float)N);

  k1_grad<<<dim3(K1_BLOCKS), dim3(1024), 0, stream>>>(X, W0, b0, W1, b1, WV, WQ, part, N);
  k2a_reduce<<<dim3(7,16), dim3(256), 0, stream>>>(part, tmp);
  k2b_reduce<<<dim3(7), dim3(256), 0, stream>>>(tmp, W0, b0, W1, b1, P, scale);
  k3_retrieve<<<dim3((N+255)/256), dim3(256), 0, stream>>>(X, WQ, P, (float*)d_out, N);
}

// Round 9
// 153.071 us; speedup vs baseline: 1.5340x; 1.5313x over previous
//
#include <hip/hip_runtime.h>
#include <hip/hip_bf16.h>

typedef __attribute__((ext_vector_type(8))) __bf16 bf16x8;
typedef __attribute__((ext_vector_type(4))) float f32x4;

union U8 { bf16x8 v; unsigned u[4]; uint2 d[2]; };

#define ALPHA 0.999f
#define THETA 0.05f

#define K1_BLOCKS 1024
// Per-row LDS record (halfs): dy@0(16) | h@16(32) | q@48(16) | dh@64(32) | pad->100.
// Row stride 100 halfs = 50 dwords, gcd(50,32)=2 -> 2-way bank aliasing (free),
// proven 0-conflict in R1. All staging writes are b64 (4 contiguous halfs),
// all forward B-frag reads are 2x b64 (8 contiguous halfs), gradient frag
// reads are the R1-proven stride-RREC u16 gathers.
#define RREC 100
#define F_DY 0
#define F_H  16
#define F_Q  48
#define F_DH 64
#define WAVE_HALFS (64*RREC)          // 6400 halfs = 12.8 KB / wave
#define SMEM_HALFS (4*WAVE_HALFS)     // 51200 B (>= 28672 B reduction region)

__device__ __forceinline__ float sigmoidf_(float z){ return 1.f/(1.f+__expf(-z)); }

__device__ __forceinline__ unsigned pk2_(float a, float b){
  union { __bf16 h[2]; unsigned u; } x; x.h[0]=(__bf16)a; x.h[1]=(__bf16)b; return x.u;
}
// unpack element r (0..3) of a packed bf16 quad
__device__ __forceinline__ float upk_(uint2 p, int r){
  unsigned u = (r<2) ? p.x : p.y;
  return (r&1) ? __uint_as_float(u & 0xffff0000u) : __uint_as_float(u << 16);
}

// ---------------- Kernel 1: gradient pass, MFMA forward+backward ----------------
// Transposed chain: compute W @ X^T so every dynamic operand is a B-fragment
// B[k=feat][col=xrow], read as 8 contiguous halfs from the [xrow][feat] LDS
// records (identical layout to the R1-proven gradient fragment reads).
// (256,2): the only measured config with no spill (cap 124) on this toolchain.
__global__ __launch_bounds__(256, 2)
void k1_grad(const float* __restrict__ X,
             const float* __restrict__ W0, const float* __restrict__ b0,
             const float* __restrict__ W1, const float* __restrict__ b1,
             const float* __restrict__ WV, const float* __restrict__ WQ,
             float* __restrict__ wsPart, int N)
{
  __shared__ __align__(16) __bf16 smem[SMEM_HALFS];
  const int tid = threadIdx.x;
  const int w = tid >> 6, l = tid & 63;
  const int g = l >> 4, c = l & 15;
  __bf16* WB = smem + w*WAVE_HALFS;

  const f32x4 zz = {0.f,0.f,0.f,0.f};

  bf16x8 ones;
  #pragma unroll
  for (int i=0;i<8;++i) ones[i] = (__bf16)1.f;

  // ---- one-time weight A-fragments (bf16, zero-padded K where K=16) ----
  // A[row = l&15][k = (l>>4)*8 + i]  (hardware-proven mapping, R1 grad path)
  U8 aWV, aWQ, aW0[2], aW1y, aW1T[2];
  #pragma unroll
  for (int i=0;i<4;++i){ aWV.u[i]=0; aWQ.u[i]=0; aW0[0].u[i]=0; aW0[1].u[i]=0; aW1T[0].u[i]=0; aW1T[1].u[i]=0; }
  if (g < 2){
    {
      const float4 u0 = *(const float4*)(WV + c*16 + g*8);
      const float4 u1 = *(const float4*)(WV + c*16 + g*8 + 4);
      aWV.u[0]=pk2_(u0.x,u0.y); aWV.u[1]=pk2_(u0.z,u0.w); aWV.u[2]=pk2_(u1.x,u1.y); aWV.u[3]=pk2_(u1.z,u1.w);
    }
    {
      const float4 u0 = *(const float4*)(WQ + c*16 + g*8);
      const float4 u1 = *(const float4*)(WQ + c*16 + g*8 + 4);
      aWQ.u[0]=pk2_(u0.x,u0.y); aWQ.u[1]=pk2_(u0.z,u0.w); aWQ.u[2]=pk2_(u1.x,u1.y); aWQ.u[3]=pk2_(u1.z,u1.w);
    }
    #pragma unroll
    for (int T=0;T<2;++T){
      const float4 u0 = *(const float4*)(W0 + (16*T + c)*16 + g*8);
      const float4 u1 = *(const float4*)(W0 + (16*T + c)*16 + g*8 + 4);
      aW0[T].u[0]=pk2_(u0.x,u0.y); aW0[T].u[1]=pk2_(u0.z,u0.w); aW0[T].u[2]=pk2_(u1.x,u1.y); aW0[T].u[3]=pk2_(u1.z,u1.w);
      // W1^T A-frag: A[row=hfeat=16T+c][k=yfeat 8g+i] = W1[8g+i][16T+c]
      float t0 = W1[(8*g+0)*32 + 16*T + c], t1 = W1[(8*g+1)*32 + 16*T + c];
      float t2 = W1[(8*g+2)*32 + 16*T + c], t3 = W1[(8*g+3)*32 + 16*T + c];
      float t4 = W1[(8*g+4)*32 + 16*T + c], t5 = W1[(8*g+5)*32 + 16*T + c];
      float t6 = W1[(8*g+6)*32 + 16*T + c], t7 = W1[(8*g+7)*32 + 16*T + c];
      aW1T[T].u[0]=pk2_(t0,t1); aW1T[T].u[1]=pk2_(t2,t3); aW1T[T].u[2]=pk2_(t4,t5); aW1T[T].u[3]=pk2_(t6,t7);
    }
  }
  { // W1 for y: full K=32, all lane groups
    const float4 u0 = *(const float4*)(W1 + c*32 + g*8);
    const float4 u1 = *(const float4*)(W1 + c*32 + g*8 + 4);
    aW1y.u[0]=pk2_(u0.x,u0.y); aW1y.u[1]=pk2_(u0.z,u0.w); aW1y.u[2]=pk2_(u1.x,u1.y); aW1y.u[3]=pk2_(u1.z,u1.w);
  }
  // bias quads: C row = (l>>4)*4 + r
  const f32x4 b0q0 = *(const f32x4*)(b0 + 4*g);
  const f32x4 b0q1 = *(const f32x4*)(b0 + 16 + 4*g);
  const f32x4 b1q  = *(const f32x4*)(b1 + 4*g);

  f32x4 acc[7] = {};

  const int nb = N >> 6;                 // 64-row batches
  const int tw = K1_BLOCKS*4;            // total waves
  const int gw = blockIdx.x*4 + w;
  const int iters = (nb + tw - 1) / tw;

  for (int it = 0; it < iters; ++it) {
    const int batch = gw + it*tw;
    if (batch < nb) {
      const float* xb = X + (size_t)batch*1024;   // 64 rows x 16

      // ---- per xrow-tile: X B-frag, SV^T -> v, SQ^T -> q (staged) ----
      uint2 vvp[4];
      #pragma unroll
      for (int t=0;t<4;++t){
        U8 bX;
        if (g < 2){
          const float4 u0 = *(const float4*)(xb + (16*t + c)*16 + g*8);
          const float4 u1 = *(const float4*)(xb + (16*t + c)*16 + g*8 + 4);
          bX.u[0]=pk2_(u0.x,u0.y); bX.u[1]=pk2_(u0.z,u0.w); bX.u[2]=pk2_(u1.x,u1.y); bX.u[3]=pk2_(u1.z,u1.w);
        } else { bX.u[0]=bX.u[1]=bX.u[2]=bX.u[3]=0; }

        f32x4 sv = __builtin_amdgcn_mfma_f32_16x16x32_bf16(aWV.v, bX.v, zz, 0,0,0);
        float v0 = sv[0]*sigmoidf_(sv[0]), v1 = sv[1]*sigmoidf_(sv[1]);
        float v2 = sv[2]*sigmoidf_(sv[2]), v3 = sv[3]*sigmoidf_(sv[3]);
        vvp[t] = make_uint2(pk2_(v0,v1), pk2_(v2,v3));

        f32x4 sq = __builtin_amdgcn_mfma_f32_16x16x32_bf16(aWQ.v, bX.v, zz, 0,0,0);
        f32x4 tq; float n2 = 0.f;
        #pragma unroll
        for (int r=0;r<4;++r){
          float s = sq[r]; float tt = s * sigmoidf_(s);
          tq[r] = tt; n2 = fmaf(tt, tt, n2);
        }
        n2 += __shfl_xor(n2, 16);
        n2 += __shfl_xor(n2, 32);
        const float inv = 1.f / fmaxf(sqrtf(n2), 1e-12f);
        *(uint2*)(WB + (16*t + c)*RREC + F_Q + 4*g) =
            make_uint2(pk2_(tq[0]*inv, tq[1]*inv), pk2_(tq[2]*inv, tq[3]*inv));
      }

      // ---- q B-frags (contiguous 8 halfs; zero for k>=16 groups) ----
      U8 bq[4];
      #pragma unroll
      for (int t=0;t<4;++t){
        if (g < 2){
          const __bf16* p = WB + (16*t + c)*RREC + F_Q + 8*g;
          bq[t].d[0] = *(const uint2*)p; bq[t].d[1] = *(const uint2*)(p + 4);
        } else { bq[t].u[0]=bq[t].u[1]=bq[t].u[2]=bq[t].u[3]=0; }
      }

      // ---- h = silu(W0 q^T + b0), stage h, keep dsilu packed ----
      uint2 dshp[2][4];
      #pragma unroll
      for (int T=0;T<2;++T){
        #pragma unroll
        for (int t=0;t<4;++t){
          f32x4 sh = __builtin_amdgcn_mfma_f32_16x16x32_bf16(aW0[T].v, bq[t].v, T? b0q1 : b0q0, 0,0,0);
          float hh[4], dd[4];
          #pragma unroll
          for (int r=0;r<4;++r){
            float s = sh[r]; float sg = sigmoidf_(s);
            hh[r] = s*sg;
            dd[r] = sg * fmaf(s, 1.f - sg, 1.f);
          }
          *(uint2*)(WB + (16*t + c)*RREC + F_H + 16*T + 4*g) =
              make_uint2(pk2_(hh[0],hh[1]), pk2_(hh[2],hh[3]));
          dshp[T][t] = make_uint2(pk2_(dd[0],dd[1]), pk2_(dd[2],dd[3]));
        }
      }

      // ---- y = silu(W1 h^T + b1); dy = (y - v)*silu'(sy), stage dy ----
      #pragma unroll
      for (int t=0;t<4;++t){
        U8 bh;
        const __bf16* p = WB + (16*t + c)*RREC + F_H + 8*g;
        bh.d[0] = *(const uint2*)p; bh.d[1] = *(const uint2*)(p + 4);
        f32x4 sy = __builtin_amdgcn_mfma_f32_16x16x32_bf16(aW1y.v, bh.v, b1q, 0,0,0);
        float dyv[4];
        #pragma unroll
        for (int r=0;r<4;++r){
          float s = sy[r]; float sg = sigmoidf_(s);
          float y = s*sg;
          float ds = sg * fmaf(s, 1.f - sg, 1.f);
          dyv[r] = (y - upk_(vvp[t], r)) * ds;
        }
        *(uint2*)(WB + (16*t + c)*RREC + F_DY + 4*g) =
            make_uint2(pk2_(dyv[0],dyv[1]), pk2_(dyv[2],dyv[3]));
      }

      // ---- dh = (W1^T dy^T) * dsilu, stage dh ----
      #pragma unroll
      for (int t=0;t<4;++t){
        U8 bdy;
        if (g < 2){
          const __bf16* p = WB + (16*t + c)*RREC + F_DY + 8*g;
          bdy.d[0] = *(const uint2*)p; bdy.d[1] = *(const uint2*)(p + 4);
        } else { bdy.u[0]=bdy.u[1]=bdy.u[2]=bdy.u[3]=0; }
        #pragma unroll
        for (int T=0;T<2;++T){
          f32x4 sd = __builtin_amdgcn_mfma_f32_16x16x32_bf16(aW1T[T].v, bdy.v, zz, 0,0,0);
          float dh0 = sd[0]*upk_(dshp[T][t],0), dh1 = sd[1]*upk_(dshp[T][t],1);
          float dh2 = sd[2]*upk_(dshp[T][t],2), dh3 = sd[3]*upk_(dshp[T][t],3);
          *(uint2*)(WB + (16*t + c)*RREC + F_DH + 16*T + 4*g) =
              make_uint2(pk2_(dh0,dh1), pk2_(dh2,dh3));
        }
      }

      // ---- gradient MFMAs (identical to R1-proven path) ----
      #pragma unroll
      for (int kc=0;kc<2;++kc){
        const int r0 = kc*32 + g*8;
        const __bf16* base = WB + r0*RREC + c;
        bf16x8 fdy, fh0, fh1, fq, fd0, fd1;
        #pragma unroll
        for (int i=0;i<8;++i){
          const __bf16* pr = base + i*RREC;
          fdy[i] = pr[F_DY];
          fh0[i] = pr[F_H];
          fh1[i] = pr[F_H + 16];
          fq[i]  = pr[F_Q];
          fd0[i] = pr[F_DH];
          fd1[i] = pr[F_DH + 16];
        }
        acc[0] = __builtin_amdgcn_mfma_f32_16x16x32_bf16(fdy, fh0, acc[0], 0,0,0); // gW1[:, 0:16]
        acc[1] = __builtin_amdgcn_mfma_f32_16x16x32_bf16(fdy, fh1, acc[1], 0,0,0); // gW1[:,16:32]
        acc[2] = __builtin_amdgcn_mfma_f32_16x16x32_bf16(fdy, ones, acc[2], 0,0,0); // gb1
        acc[3] = __builtin_amdgcn_mfma_f32_16x16x32_bf16(fd0, fq, acc[3], 0,0,0);   // gW0[0:16, :]
        acc[4] = __builtin_amdgcn_mfma_f32_16x16x32_bf16(fd1, fq, acc[4], 0,0,0);   // gW0[16:32,:]
        acc[5] = __builtin_amdgcn_mfma_f32_16x16x32_bf16(fd0, ones, acc[5], 0,0,0); // gb0[0:16]
        acc[6] = __builtin_amdgcn_mfma_f32_16x16x32_bf16(fd1, ones, acc[6], 0,0,0); // gb0[16:32]
      }
    }
  }

  // ---- block reduction over the 4 waves (reuse LDS as float) ----
  __syncthreads();
  float* red = (float*)smem;
  #pragma unroll
  for (int a=0;a<7;++a){
    #pragma unroll
    for (int r=0;r<4;++r)
      red[w*1792 + a*256 + l*4 + r] = acc[a][r];
  }
  __syncthreads();
  for (int s = tid; s < 1792; s += 256){
    float sum = red[s] + red[1792+s] + red[2*1792+s] + red[3*1792+s];
    wsPart[(size_t)blockIdx.x*1792 + s] = sum;
  }
}

// ---------------- Kernel 2a: partial reduce (1024 -> 16 chunks) ----------------
__global__ void k2a_reduce(const float* __restrict__ wsPart, float* __restrict__ tmp)
{
  const int s = blockIdx.x*256 + threadIdx.x;   // 0..1791 (grid.x = 7)
  const int c = blockIdx.y;                     // 0..15
  float g = 0.f;
  #pragma unroll 8
  for (int j=0;j<64;++j) g += wsPart[(size_t)(c*64+j)*1792 + s];
  tmp[(size_t)c*1792 + s] = g;
}

// ---------------- Kernel 2b: final reduce, form updated params ----------------
__global__ void k2b_reduce(const float* __restrict__ tmp,
                           const float* __restrict__ W0, const float* __restrict__ b0,
                           const float* __restrict__ W1, const float* __restrict__ b1,
                           float* __restrict__ P, float scale)
{
  int s = blockIdx.x*256 + threadIdx.x;
  if (s >= 1792) return;
  float g = 0.f;
  #pragma unroll
  for (int c=0;c<16;++c) g += tmp[(size_t)c*1792 + s];
  g *= scale;   // 2/(N*16)
  int a = s >> 8, l = (s >> 2) & 63, r = s & 3;
  int m = ((l>>4)<<2) + r, n = l & 15;
  // P layout (floats): W0[0..511], b0[512..543], W1[544..1055], b1[1056..1071]
  if (a==0)      P[544 + m*32 + n]       = ALPHA*W1[m*32+n]        - THETA*g;
  else if (a==1) P[544 + m*32 + 16 + n]  = ALPHA*W1[m*32+16+n]     - THETA*g;
  else if (a==2){ if (n==0) P[1056 + m]  = ALPHA*b1[m]             - THETA*g; }
  else if (a==3) P[m*16 + n]             = ALPHA*W0[m*16+n]        - THETA*g;
  else if (a==4) P[(16+m)*16 + n]        = ALPHA*W0[(16+m)*16+n]   - THETA*g;
  else if (a==5){ if (n==0) P[512 + m]   = ALPHA*b0[m]             - THETA*g; }
  else           { if (n==0) P[512+16+m] = ALPHA*b0[16+m]          - THETA*g; }
}

// ---------------- Kernel 3: retrieve pass (f32, unchanged math) ----------------
__global__ __launch_bounds__(256, 2)
void k3_retrieve(const float* __restrict__ X, const float* __restrict__ WQ,
                 const float* __restrict__ P, float* __restrict__ out, int N)
{
  int row = blockIdx.x*256 + threadIdx.x;
  if (row >= N) return;
  const float* xp = X + (size_t)row*16;
  float x[16];
  {
    const float4* xv = (const float4*)xp;
    float4 t0=xv[0], t1=xv[1], t2=xv[2], t3=xv[3];
    x[0]=t0.x; x[1]=t0.y; x[2]=t0.z; x[3]=t0.w;
    x[4]=t1.x; x[5]=t1.y; x[6]=t1.z; x[7]=t1.w;
    x[8]=t2.x; x[9]=t2.y; x[10]=t2.z; x[11]=t2.w;
    x[12]=t3.x; x[13]=t3.y; x[14]=t3.z; x[15]=t3.w;
  }
  // r = silu(l2norm(x @ WQ^T))   (norm BEFORE silu here)
  float rq[16]; float n2 = 0.f;
  #pragma unroll
  for (int k=0;k<16;++k){
    float s = 0.f;
    #pragma unroll
    for (int d=0;d<16;++d) s = fmaf(x[d], WQ[k*16+d], s);
    rq[k] = s; n2 = fmaf(s, s, n2);
  }
  const float inv = 1.f / fmaxf(sqrtf(n2), 1e-12f);
  #pragma unroll
  for (int k=0;k<16;++k){
    float z = rq[k]*inv;
    rq[k] = z * sigmoidf_(z);
  }
  // h = silu(r @ W0'^T + b0')
  float h[32];
  #pragma unroll
  for (int j=0;j<32;++j){
    float s = P[512+j];
    #pragma unroll
    for (int d=0;d<16;++d) s = fmaf(rq[d], P[j*16+d], s);
    h[j] = s * sigmoidf_(s);
  }
  // o = silu(h @ W1'^T + b1')
  float o[16];
  #pragma unroll
  for (int k=0;k<16;++k){
    float s = P[1056+k];
    #pragma unroll
    for (int j=0;j<32;++j) s = fmaf(h[j], P[544 + k*32 + j], s);
    o[k] = s * sigmoidf_(s);
  }
  float4* op = (float4*)(out + (size_t)row*16);
  op[0] = make_float4(o[0],o[1],o[2],o[3]);
  op[1] = make_float4(o[4],o[5],o[6],o[7]);
  op[2] = make_float4(o[8],o[9],o[10],o[11]);
  op[3] = make_float4(o[12],o[13],o[14],o[15]);
}

extern "C" void kernel_launch(void* const* d_in, const int* in_sizes, int n_in,
                              void* d_out, int out_size, void* d_ws, size_t ws_size,
                              hipStream_t stream)
{
  const float* X  = (const float*)d_in[0];
  const float* W0 = (const float*)d_in[1];
  const float* b0 = (const float*)d_in[2];
  const float* W1 = (const float*)d_in[3];
  const float* b1 = (const float*)d_in[4];
  const float* WV = (const float*)d_in[6];
  const float* WQ = (const float*)d_in[7];
  float* ws   = (float*)d_ws;
  float* P    = ws;                         // 1072 floats of updated params
  float* part = ws + 2048;                  // 1024*1792 floats of partials
  float* tmp  = part + (size_t)K1_BLOCKS*1792;  // 16*1792 floats

  const int N = in_sizes[0] / 16;
  const float scale = 2.f / (16.f * (float)N);

  k1_grad<<<dim3(K1_BLOCKS), dim3(256), 0, stream>>>(X, W0, b0, W1, b1, WV, WQ, part, N);
  k2a_reduce<<<dim3(7,16), dim3(256), 0, stream>>>(part, tmp);
  k2b_reduce<<<dim3(7), dim3(256), 0, stream>>>(tmp, W0, b0, W1, b1, P, scale);
  k3_retrieve<<<dim3((N+255)/256), dim3(256), 0, stream>>>(X, WQ, P, (float*)d_out, N);
}

// Round 10
// 144.648 us; speedup vs baseline: 1.6233x; 1.0582x over previous
//
#include <hip/hip_runtime.h>
#include <hip/hip_bf16.h>

typedef __attribute__((ext_vector_type(8))) __bf16 bf16x8;
typedef __attribute__((ext_vector_type(4))) float f32x4;

union U8 { bf16x8 v; unsigned u[4]; uint2 d[2]; };

#define ALPHA 0.999f
#define THETA 0.05f

#define K1_BLOCKS 1024
#define K3_BLOCKS 1024
// k1 per-row LDS record (halfs): dy@0(16) | h@16(32) | q@48(16) | dh@64(32) | pad->100.
// Row stride 100 halfs = 50 dwords, gcd(50,32)=2 -> 2-way bank aliasing (free).
#define RREC 100
#define F_DY 0
#define F_H  16
#define F_Q  48
#define F_DH 64
#define WAVE_HALFS (64*RREC)          // 6400 halfs = 12.8 KB / wave
#define SMEM_HALFS (4*WAVE_HALFS)     // 51200 B (>= 28672 B reduction region)

// k3 per-row record (same stride/banking): qhi@0(16) | qlo@16(16) | hhi@32(32) | hlo@64(32)
#define R3 100
#define Q_HI 0
#define Q_LO 16
#define H_HI 32
#define H_LO 64

__device__ __forceinline__ float sigmoidf_(float z){ return 1.f/(1.f+__expf(-z)); }

__device__ __forceinline__ unsigned pk2_(float a, float b){
  union { __bf16 h[2]; unsigned u; } x; x.h[0]=(__bf16)a; x.h[1]=(__bf16)b; return x.u;
}
// unpack element r (0..3) of a packed bf16 quad
__device__ __forceinline__ float upk_(uint2 p, int r){
  unsigned u = (r<2) ? p.x : p.y;
  return (r&1) ? __uint_as_float(u & 0xffff0000u) : __uint_as_float(u << 16);
}
// split (a,b) into bf16 hi pair + bf16 lo-residual pair (hi+lo ~ f32 exact to 2^-17)
__device__ __forceinline__ void splitpk_(float a, float b, unsigned &uh, unsigned &ul){
  unsigned h = pk2_(a,b);
  float ah = __uint_as_float(h << 16);
  float bh = __uint_as_float(h & 0xffff0000u);
  uh = h; ul = pk2_(a - ah, b - bh);
}
// load 8 f32 and split into hi/lo bf16x8 fragments
__device__ __forceinline__ void load_split8_(const float* p, U8 &H, U8 &L){
  const float4 u0 = *(const float4*)p;
  const float4 u1 = *(const float4*)(p+4);
  splitpk_(u0.x,u0.y,H.u[0],L.u[0]); splitpk_(u0.z,u0.w,H.u[1],L.u[1]);
  splitpk_(u1.x,u1.y,H.u[2],L.u[2]); splitpk_(u1.z,u1.w,H.u[3],L.u[3]);
}

// ---------------- Kernel 1: gradient pass, MFMA forward+backward (R9, proven 87us) ----------------
__global__ __launch_bounds__(256, 2)
void k1_grad(const float* __restrict__ X,
             const float* __restrict__ W0, const float* __restrict__ b0,
             const float* __restrict__ W1, const float* __restrict__ b1,
             const float* __restrict__ WV, const float* __restrict__ WQ,
             float* __restrict__ wsPart, int N)
{
  __shared__ __align__(16) __bf16 smem[SMEM_HALFS];
  const int tid = threadIdx.x;
  const int w = tid >> 6, l = tid & 63;
  const int g = l >> 4, c = l & 15;
  __bf16* WB = smem + w*WAVE_HALFS;

  const f32x4 zz = {0.f,0.f,0.f,0.f};

  bf16x8 ones;
  #pragma unroll
  for (int i=0;i<8;++i) ones[i] = (__bf16)1.f;

  U8 aWV, aWQ, aW0[2], aW1y, aW1T[2];
  #pragma unroll
  for (int i=0;i<4;++i){ aWV.u[i]=0; aWQ.u[i]=0; aW0[0].u[i]=0; aW0[1].u[i]=0; aW1T[0].u[i]=0; aW1T[1].u[i]=0; }
  if (g < 2){
    {
      const float4 u0 = *(const float4*)(WV + c*16 + g*8);
      const float4 u1 = *(const float4*)(WV + c*16 + g*8 + 4);
      aWV.u[0]=pk2_(u0.x,u0.y); aWV.u[1]=pk2_(u0.z,u0.w); aWV.u[2]=pk2_(u1.x,u1.y); aWV.u[3]=pk2_(u1.z,u1.w);
    }
    {
      const float4 u0 = *(const float4*)(WQ + c*16 + g*8);
      const float4 u1 = *(const float4*)(WQ + c*16 + g*8 + 4);
      aWQ.u[0]=pk2_(u0.x,u0.y); aWQ.u[1]=pk2_(u0.z,u0.w); aWQ.u[2]=pk2_(u1.x,u1.y); aWQ.u[3]=pk2_(u1.z,u1.w);
    }
    #pragma unroll
    for (int T=0;T<2;++T){
      const float4 u0 = *(const float4*)(W0 + (16*T + c)*16 + g*8);
      const float4 u1 = *(const float4*)(W0 + (16*T + c)*16 + g*8 + 4);
      aW0[T].u[0]=pk2_(u0.x,u0.y); aW0[T].u[1]=pk2_(u0.z,u0.w); aW0[T].u[2]=pk2_(u1.x,u1.y); aW0[T].u[3]=pk2_(u1.z,u1.w);
      float t0 = W1[(8*g+0)*32 + 16*T + c], t1 = W1[(8*g+1)*32 + 16*T + c];
      float t2 = W1[(8*g+2)*32 + 16*T + c], t3 = W1[(8*g+3)*32 + 16*T + c];
      float t4 = W1[(8*g+4)*32 + 16*T + c], t5 = W1[(8*g+5)*32 + 16*T + c];
      float t6 = W1[(8*g+6)*32 + 16*T + c], t7 = W1[(8*g+7)*32 + 16*T + c];
      aW1T[T].u[0]=pk2_(t0,t1); aW1T[T].u[1]=pk2_(t2,t3); aW1T[T].u[2]=pk2_(t4,t5); aW1T[T].u[3]=pk2_(t6,t7);
    }
  }
  {
    const float4 u0 = *(const float4*)(W1 + c*32 + g*8);
    const float4 u1 = *(const float4*)(W1 + c*32 + g*8 + 4);
    aW1y.u[0]=pk2_(u0.x,u0.y); aW1y.u[1]=pk2_(u0.z,u0.w); aW1y.u[2]=pk2_(u1.x,u1.y); aW1y.u[3]=pk2_(u1.z,u1.w);
  }
  const f32x4 b0q0 = *(const f32x4*)(b0 + 4*g);
  const f32x4 b0q1 = *(const f32x4*)(b0 + 16 + 4*g);
  const f32x4 b1q  = *(const f32x4*)(b1 + 4*g);

  f32x4 acc[7] = {};

  const int nb = N >> 6;
  const int tw = K1_BLOCKS*4;
  const int gw = blockIdx.x*4 + w;
  const int iters = (nb + tw - 1) / tw;

  for (int it = 0; it < iters; ++it) {
    const int batch = gw + it*tw;
    if (batch < nb) {
      const float* xb = X + (size_t)batch*1024;

      uint2 vvp[4];
      #pragma unroll
      for (int t=0;t<4;++t){
        U8 bX;
        if (g < 2){
          const float4 u0 = *(const float4*)(xb + (16*t + c)*16 + g*8);
          const float4 u1 = *(const float4*)(xb + (16*t + c)*16 + g*8 + 4);
          bX.u[0]=pk2_(u0.x,u0.y); bX.u[1]=pk2_(u0.z,u0.w); bX.u[2]=pk2_(u1.x,u1.y); bX.u[3]=pk2_(u1.z,u1.w);
        } else { bX.u[0]=bX.u[1]=bX.u[2]=bX.u[3]=0; }

        f32x4 sv = __builtin_amdgcn_mfma_f32_16x16x32_bf16(aWV.v, bX.v, zz, 0,0,0);
        float v0 = sv[0]*sigmoidf_(sv[0]), v1 = sv[1]*sigmoidf_(sv[1]);
        float v2 = sv[2]*sigmoidf_(sv[2]), v3 = sv[3]*sigmoidf_(sv[3]);
        vvp[t] = make_uint2(pk2_(v0,v1), pk2_(v2,v3));

        f32x4 sq = __builtin_amdgcn_mfma_f32_16x16x32_bf16(aWQ.v, bX.v, zz, 0,0,0);
        f32x4 tq; float n2 = 0.f;
        #pragma unroll
        for (int r=0;r<4;++r){
          float s = sq[r]; float tt = s * sigmoidf_(s);
          tq[r] = tt; n2 = fmaf(tt, tt, n2);
        }
        n2 += __shfl_xor(n2, 16);
        n2 += __shfl_xor(n2, 32);
        const float inv = 1.f / fmaxf(sqrtf(n2), 1e-12f);
        *(uint2*)(WB + (16*t + c)*RREC + F_Q + 4*g) =
            make_uint2(pk2_(tq[0]*inv, tq[1]*inv), pk2_(tq[2]*inv, tq[3]*inv));
      }

      U8 bq[4];
      #pragma unroll
      for (int t=0;t<4;++t){
        if (g < 2){
          const __bf16* p = WB + (16*t + c)*RREC + F_Q + 8*g;
          bq[t].d[0] = *(const uint2*)p; bq[t].d[1] = *(const uint2*)(p + 4);
        } else { bq[t].u[0]=bq[t].u[1]=bq[t].u[2]=bq[t].u[3]=0; }
      }

      uint2 dshp[2][4];
      #pragma unroll
      for (int T=0;T<2;++T){
        #pragma unroll
        for (int t=0;t<4;++t){
          f32x4 sh = __builtin_amdgcn_mfma_f32_16x16x32_bf16(aW0[T].v, bq[t].v, T? b0q1 : b0q0, 0,0,0);
          float hh[4], dd[4];
          #pragma unroll
          for (int r=0;r<4;++r){
            float s = sh[r]; float sg = sigmoidf_(s);
            hh[r] = s*sg;
            dd[r] = sg * fmaf(s, 1.f - sg, 1.f);
          }
          *(uint2*)(WB + (16*t + c)*RREC + F_H + 16*T + 4*g) =
              make_uint2(pk2_(hh[0],hh[1]), pk2_(hh[2],hh[3]));
          dshp[T][t] = make_uint2(pk2_(dd[0],dd[1]), pk2_(dd[2],dd[3]));
        }
      }

      #pragma unroll
      for (int t=0;t<4;++t){
        U8 bh;
        const __bf16* p = WB + (16*t + c)*RREC + F_H + 8*g;
        bh.d[0] = *(const uint2*)p; bh.d[1] = *(const uint2*)(p + 4);
        f32x4 sy = __builtin_amdgcn_mfma_f32_16x16x32_bf16(aW1y.v, bh.v, b1q, 0,0,0);
        float dyv[4];
        #pragma unroll
        for (int r=0;r<4;++r){
          float s = sy[r]; float sg = sigmoidf_(s);
          float y = s*sg;
          float ds = sg * fmaf(s, 1.f - sg, 1.f);
          dyv[r] = (y - upk_(vvp[t], r)) * ds;
        }
        *(uint2*)(WB + (16*t + c)*RREC + F_DY + 4*g) =
            make_uint2(pk2_(dyv[0],dyv[1]), pk2_(dyv[2],dyv[3]));
      }

      #pragma unroll
      for (int t=0;t<4;++t){
        U8 bdy;
        if (g < 2){
          const __bf16* p = WB + (16*t + c)*RREC + F_DY + 8*g;
          bdy.d[0] = *(const uint2*)p; bdy.d[1] = *(const uint2*)(p + 4);
        } else { bdy.u[0]=bdy.u[1]=bdy.u[2]=bdy.u[3]=0; }
        #pragma unroll
        for (int T=0;T<2;++T){
          f32x4 sd = __builtin_amdgcn_mfma_f32_16x16x32_bf16(aW1T[T].v, bdy.v, zz, 0,0,0);
          float dh0 = sd[0]*upk_(dshp[T][t],0), dh1 = sd[1]*upk_(dshp[T][t],1);
          float dh2 = sd[2]*upk_(dshp[T][t],2), dh3 = sd[3]*upk_(dshp[T][t],3);
          *(uint2*)(WB + (16*t + c)*RREC + F_DH + 16*T + 4*g) =
              make_uint2(pk2_(dh0,dh1), pk2_(dh2,dh3));
        }
      }

      #pragma unroll
      for (int kc=0;kc<2;++kc){
        const int r0 = kc*32 + g*8;
        const __bf16* base = WB + r0*RREC + c;
        bf16x8 fdy, fh0, fh1, fq, fd0, fd1;
        #pragma unroll
        for (int i=0;i<8;++i){
          const __bf16* pr = base + i*RREC;
          fdy[i] = pr[F_DY];
          fh0[i] = pr[F_H];
          fh1[i] = pr[F_H + 16];
          fq[i]  = pr[F_Q];
          fd0[i] = pr[F_DH];
          fd1[i] = pr[F_DH + 16];
        }
        acc[0] = __builtin_amdgcn_mfma_f32_16x16x32_bf16(fdy, fh0, acc[0], 0,0,0);
        acc[1] = __builtin_amdgcn_mfma_f32_16x16x32_bf16(fdy, fh1, acc[1], 0,0,0);
        acc[2] = __builtin_amdgcn_mfma_f32_16x16x32_bf16(fdy, ones, acc[2], 0,0,0);
        acc[3] = __builtin_amdgcn_mfma_f32_16x16x32_bf16(fd0, fq, acc[3], 0,0,0);
        acc[4] = __builtin_amdgcn_mfma_f32_16x16x32_bf16(fd1, fq, acc[4], 0,0,0);
        acc[5] = __builtin_amdgcn_mfma_f32_16x16x32_bf16(fd0, ones, acc[5], 0,0,0);
        acc[6] = __builtin_amdgcn_mfma_f32_16x16x32_bf16(fd1, ones, acc[6], 0,0,0);
      }
    }
  }

  __syncthreads();
  float* red = (float*)smem;
  #pragma unroll
  for (int a=0;a<7;++a){
    #pragma unroll
    for (int r=0;r<4;++r)
      red[w*1792 + a*256 + l*4 + r] = acc[a][r];
  }
  __syncthreads();
  for (int s = tid; s < 1792; s += 256){
    float sum = red[s] + red[1792+s] + red[2*1792+s] + red[3*1792+s];
    wsPart[(size_t)blockIdx.x*1792 + s] = sum;
  }
}

// ---------------- Kernel 2a: partial reduce (1024 -> 16 chunks) ----------------
__global__ void k2a_reduce(const float* __restrict__ wsPart, float* __restrict__ tmp)
{
  const int s = blockIdx.x*256 + threadIdx.x;
  const int c = blockIdx.y;
  float g = 0.f;
  #pragma unroll 8
  for (int j=0;j<64;++j) g += wsPart[(size_t)(c*64+j)*1792 + s];
  tmp[(size_t)c*1792 + s] = g;
}

// ---------------- Kernel 2b: final reduce, form updated params ----------------
__global__ void k2b_reduce(const float* __restrict__ tmp,
                           const float* __restrict__ W0, const float* __restrict__ b0,
                           const float* __restrict__ W1, const float* __restrict__ b1,
                           float* __restrict__ P, float scale)
{
  int s = blockIdx.x*256 + threadIdx.x;
  if (s >= 1792) return;
  float g = 0.f;
  #pragma unroll
  for (int c=0;c<16;++c) g += tmp[(size_t)c*1792 + s];
  g *= scale;
  int a = s >> 8, l = (s >> 2) & 63, r = s & 3;
  int m = ((l>>4)<<2) + r, n = l & 15;
  if (a==0)      P[544 + m*32 + n]       = ALPHA*W1[m*32+n]        - THETA*g;
  else if (a==1) P[544 + m*32 + 16 + n]  = ALPHA*W1[m*32+16+n]     - THETA*g;
  else if (a==2){ if (n==0) P[1056 + m]  = ALPHA*b1[m]             - THETA*g; }
  else if (a==3) P[m*16 + n]             = ALPHA*W0[m*16+n]        - THETA*g;
  else if (a==4) P[(16+m)*16 + n]        = ALPHA*W0[(16+m)*16+n]   - THETA*g;
  else if (a==5){ if (n==0) P[512 + m]   = ALPHA*b0[m]             - THETA*g; }
  else           { if (n==0) P[512+16+m] = ALPHA*b0[16+m]          - THETA*g; }
}

// ---------------- Kernel 3: retrieve pass, MFMA with hi/lo bf16 split ----------------
// Same transposed structure as k1. Precision: each f32 operand is split into
// bf16 hi + bf16 lo-residual; D = Wh*xh + Wh*xl + Wl*xh gives ~2^-17 relative
// error (Wl*xl term ~2^-18 dropped) -- the update path feeds the output
// directly (no theta damping), so plain-bf16 would be borderline vs threshold.
__global__ __launch_bounds__(256, 2)
void k3_retrieve(const float* __restrict__ X, const float* __restrict__ WQ,
                 const float* __restrict__ P, float* __restrict__ out, int N)
{
  __shared__ __align__(16) __bf16 smem[4*64*R3];
  const int tid = threadIdx.x;
  const int w = tid >> 6, l = tid & 63;
  const int g = l >> 4, c = l & 15;
  __bf16* WB = smem + w*64*R3;
  const f32x4 zz = {0.f,0.f,0.f,0.f};

  U8 aQh, aQl, aW0h[2], aW0l[2], aW1h, aW1l;
  #pragma unroll
  for (int i=0;i<4;++i){
    aQh.u[i]=aQl.u[i]=0;
    aW0h[0].u[i]=aW0l[0].u[i]=0; aW0h[1].u[i]=aW0l[1].u[i]=0;
  }
  if (g < 2){
    load_split8_(WQ + c*16 + g*8, aQh, aQl);
    #pragma unroll
    for (int T=0;T<2;++T) load_split8_(P + (16*T + c)*16 + g*8, aW0h[T], aW0l[T]);
  }
  load_split8_(P + 544 + c*32 + g*8, aW1h, aW1l);
  const f32x4 b0q0 = *(const f32x4*)(P + 512 + 4*g);
  const f32x4 b0q1 = *(const f32x4*)(P + 528 + 4*g);
  const f32x4 b1q  = *(const f32x4*)(P + 1056 + 4*g);

  const int nb = N >> 6;
  const int tw = K3_BLOCKS*4;
  const int gw = blockIdx.x*4 + w;
  const int iters = (nb + tw - 1) / tw;

  for (int it=0; it<iters; ++it){
    const int batch = gw + it*tw;
    if (batch < nb){
      const float* xb = X + (size_t)batch*1024;

      // ---- s = WQ x^T (hi/lo), l2norm over 16 feats, silu, stage q hi/lo ----
      #pragma unroll
      for (int t=0;t<4;++t){
        U8 bXh, bXl;
        if (g < 2){ load_split8_(xb + (16*t + c)*16 + g*8, bXh, bXl); }
        else { bXh.u[0]=bXh.u[1]=bXh.u[2]=bXh.u[3]=0; bXl=bXh; }
        f32x4 s = __builtin_amdgcn_mfma_f32_16x16x32_bf16(aQl.v, bXh.v, zz, 0,0,0);
        s = __builtin_amdgcn_mfma_f32_16x16x32_bf16(aQh.v, bXl.v, s, 0,0,0);
        s = __builtin_amdgcn_mfma_f32_16x16x32_bf16(aQh.v, bXh.v, s, 0,0,0);
        float n2 = 0.f;
        #pragma unroll
        for (int r=0;r<4;++r) n2 = fmaf(s[r], s[r], n2);
        n2 += __shfl_xor(n2, 16);
        n2 += __shfl_xor(n2, 32);
        const float inv = 1.f / fmaxf(sqrtf(n2), 1e-12f);
        float qv[4];
        #pragma unroll
        for (int r=0;r<4;++r){ float z = s[r]*inv; qv[r] = z * sigmoidf_(z); }
        unsigned qh0,ql0,qh1,ql1;
        splitpk_(qv[0],qv[1],qh0,ql0); splitpk_(qv[2],qv[3],qh1,ql1);
        __bf16* R = WB + (16*t + c)*R3;
        *(uint2*)(R + Q_HI + 4*g) = make_uint2(qh0,qh1);
        *(uint2*)(R + Q_LO + 4*g) = make_uint2(ql0,ql1);
      }

      U8 bqh[4], bql[4];
      #pragma unroll
      for (int t=0;t<4;++t){
        if (g < 2){
          const __bf16* p = WB + (16*t + c)*R3;
          bqh[t].d[0] = *(const uint2*)(p + Q_HI + 8*g); bqh[t].d[1] = *(const uint2*)(p + Q_HI + 8*g + 4);
          bql[t].d[0] = *(const uint2*)(p + Q_LO + 8*g); bql[t].d[1] = *(const uint2*)(p + Q_LO + 8*g + 4);
        } else {
          bqh[t].u[0]=bqh[t].u[1]=bqh[t].u[2]=bqh[t].u[3]=0; bql[t]=bqh[t];
        }
      }

      // ---- h = silu(W0' q^T + b0') (hi/lo), stage h hi/lo ----
      #pragma unroll
      for (int T=0;T<2;++T){
        #pragma unroll
        for (int t=0;t<4;++t){
          f32x4 sh = __builtin_amdgcn_mfma_f32_16x16x32_bf16(aW0l[T].v, bqh[t].v, T? b0q1 : b0q0, 0,0,0);
          sh = __builtin_amdgcn_mfma_f32_16x16x32_bf16(aW0h[T].v, bql[t].v, sh, 0,0,0);
          sh = __builtin_amdgcn_mfma_f32_16x16x32_bf16(aW0h[T].v, bqh[t].v, sh, 0,0,0);
          float hv[4];
          #pragma unroll
          for (int r=0;r<4;++r){ float s = sh[r]; hv[r] = s * sigmoidf_(s); }
          unsigned hh0,hl0,hh1,hl1;
          splitpk_(hv[0],hv[1],hh0,hl0); splitpk_(hv[2],hv[3],hh1,hl1);
          __bf16* R = WB + (16*t + c)*R3;
          *(uint2*)(R + H_HI + 16*T + 4*g) = make_uint2(hh0,hh1);
          *(uint2*)(R + H_LO + 16*T + 4*g) = make_uint2(hl0,hl1);
        }
      }

      // ---- o = silu(W1' h^T + b1') (hi/lo), coalesced float4 write ----
      #pragma unroll
      for (int t=0;t<4;++t){
        U8 bhh, bhl;
        const __bf16* p = WB + (16*t + c)*R3;
        bhh.d[0] = *(const uint2*)(p + H_HI + 8*g); bhh.d[1] = *(const uint2*)(p + H_HI + 8*g + 4);
        bhl.d[0] = *(const uint2*)(p + H_LO + 8*g); bhl.d[1] = *(const uint2*)(p + H_LO + 8*g + 4);
        f32x4 sy = __builtin_amdgcn_mfma_f32_16x16x32_bf16(aW1l.v, bhh.v, b1q, 0,0,0);
        sy = __builtin_amdgcn_mfma_f32_16x16x32_bf16(aW1h.v, bhl.v, sy, 0,0,0);
        sy = __builtin_amdgcn_mfma_f32_16x16x32_bf16(aW1h.v, bhh.v, sy, 0,0,0);
        float4 o;
        o.x = sy[0]*sigmoidf_(sy[0]);
        o.y = sy[1]*sigmoidf_(sy[1]);
        o.z = sy[2]*sigmoidf_(sy[2]);
        o.w = sy[3]*sigmoidf_(sy[3]);
        *(float4*)(out + ((size_t)batch*64 + 16*t + c)*16 + 4*g) = o;
      }
    }
  }
}

extern "C" void kernel_launch(void* const* d_in, const int* in_sizes, int n_in,
                              void* d_out, int out_size, void* d_ws, size_t ws_size,
                              hipStream_t stream)
{
  const float* X  = (const float*)d_in[0];
  const float* W0 = (const float*)d_in[1];
  const float* b0 = (const float*)d_in[2];
  const float* W1 = (const float*)d_in[3];
  const float* b1 = (const float*)d_in[4];
  const float* WV = (const float*)d_in[6];
  const float* WQ = (const float*)d_in[7];
  float* ws   = (float*)d_ws;
  float* P    = ws;                         // 1072 floats of updated params
  float* part = ws + 2048;                  // 1024*1792 floats of partials
  float* tmp  = part + (size_t)K1_BLOCKS*1792;  // 16*1792 floats

  const int N = in_sizes[0] / 16;
  const float scale = 2.f / (16.f * (float)N);

  k1_grad<<<dim3(K1_BLOCKS), dim3(256), 0, stream>>>(X, W0, b0, W1, b1, WV, WQ, part, N);
  k2a_reduce<<<dim3(7,16), dim3(256), 0, stream>>>(part, tmp);
  k2b_reduce<<<dim3(7), dim3(256), 0, stream>>>(tmp, W0, b0, W1, b1, P, scale);
  k3_retrieve<<<dim3(K3_BLOCKS), dim3(256), 0, stream>>>(X, WQ, P, (float*)d_out, N);
}